// Round 4
// baseline (1439.256 us; speedup 1.0000x reference)
//
#include <hip/hip_runtime.h>
#include <hip/hip_bf16.h>

typedef __bf16 bf16;
typedef __bf16 bf16x8 __attribute__((ext_vector_type(8)));
typedef __bf16 bf16x4 __attribute__((ext_vector_type(4)));
typedef float  f32x4  __attribute__((ext_vector_type(4)));

#define MFMA16(a, b, c) __builtin_amdgcn_mfma_f32_16x16x32_bf16(a, b, c, 0, 0, 0)

// ---------------------------------------------------------------------------
// GEMM: C[M,N] = A[M,K] * B[N,K]^T.  A row stride lda (elements).
// AF32/BF32: operand is float32 in global memory -> convert to bf16 in LDS
// staging.  EPI 0: Out=bf16.  EPI 1: Out=f32 = acc + Res.  EPI 2: Out=f32.
// Block 256 thr (4 waves, 2x2), tile 128x128x32.
// ---------------------------------------------------------------------------
template <int EPI, int AF32, int BF32>
__global__ __launch_bounds__(256) void gemm_bt(
    const void* __restrict__ Av, const void* __restrict__ Bv,
    const float* __restrict__ Res, void* __restrict__ Out,
    int Ntot, int Ktot, int lda)
{
    __shared__ __align__(16) bf16 As[128][40];
    __shared__ __align__(16) bf16 Bs[128][40];
    const int tid  = threadIdx.x;
    const int wave = tid >> 6, lane = tid & 63;
    const int quad = lane >> 4, l16 = lane & 15;
    const int wm = wave >> 1, wn = wave & 1;
    const int rowBase = blockIdx.y * 128, colBase = blockIdx.x * 128;

    f32x4 acc[4][4];
    const f32x4 z4 = {0.f, 0.f, 0.f, 0.f};
#pragma unroll
    for (int i = 0; i < 4; i++)
#pragma unroll
        for (int j = 0; j < 4; j++) acc[i][j] = z4;

    for (int kt = 0; kt < Ktot; kt += 32) {
        __syncthreads();
#pragma unroll
        for (int p = 0; p < 2; p++) {
            int ch = p * 256 + tid;
            int r = ch >> 2, c8 = (ch & 3) << 3;
            if (AF32) {
                const float* s = (const float*)Av + (size_t)(rowBase + r) * lda + kt + c8;
                float4 u0 = *(const float4*)s, u1 = *(const float4*)(s + 4);
                bf16x8 t;
                t[0] = (bf16)u0.x; t[1] = (bf16)u0.y; t[2] = (bf16)u0.z; t[3] = (bf16)u0.w;
                t[4] = (bf16)u1.x; t[5] = (bf16)u1.y; t[6] = (bf16)u1.z; t[7] = (bf16)u1.w;
                *(bf16x8*)&As[r][c8] = t;
            } else {
                *(bf16x8*)&As[r][c8] =
                    *(const bf16x8*)((const bf16*)Av + (size_t)(rowBase + r) * lda + kt + c8);
            }
            if (BF32) {
                const float* s = (const float*)Bv + (size_t)(colBase + r) * Ktot + kt + c8;
                float4 u0 = *(const float4*)s, u1 = *(const float4*)(s + 4);
                bf16x8 t;
                t[0] = (bf16)u0.x; t[1] = (bf16)u0.y; t[2] = (bf16)u0.z; t[3] = (bf16)u0.w;
                t[4] = (bf16)u1.x; t[5] = (bf16)u1.y; t[6] = (bf16)u1.z; t[7] = (bf16)u1.w;
                *(bf16x8*)&Bs[r][c8] = t;
            } else {
                *(bf16x8*)&Bs[r][c8] =
                    *(const bf16x8*)((const bf16*)Bv + (size_t)(colBase + r) * Ktot + kt + c8);
            }
        }
        __syncthreads();
        bf16x8 af[4], bfr[4];
#pragma unroll
        for (int i = 0; i < 4; i++)
            af[i] = *(const bf16x8*)&As[wm * 64 + i * 16 + l16][quad * 8];
#pragma unroll
        for (int j = 0; j < 4; j++)
            bfr[j] = *(const bf16x8*)&Bs[wn * 64 + j * 16 + l16][quad * 8];
#pragma unroll
        for (int i = 0; i < 4; i++)
#pragma unroll
            for (int j = 0; j < 4; j++)
                acc[i][j] = MFMA16(af[i], bfr[j], acc[i][j]);
    }

    // C/D layout: row = quad*4 + r, col = l16 (verified m89/m91)
#pragma unroll
    for (int i = 0; i < 4; i++) {
        int row0 = rowBase + wm * 64 + i * 16 + quad * 4;
#pragma unroll
        for (int j = 0; j < 4; j++) {
            int col = colBase + wn * 64 + j * 16 + l16;
#pragma unroll
            for (int r = 0; r < 4; r++) {
                size_t off = (size_t)(row0 + r) * Ntot + col;
                float v = acc[i][j][r];
                if (EPI == 0)      ((bf16*)Out)[off]  = (bf16)v;
                else if (EPI == 1) ((float*)Out)[off] = v + Res[off];
                else               ((float*)Out)[off] = v;
            }
        }
    }
}

// ---------------------------------------------------------------------------
// RMSNorm: one row per block, f32 in (X) + f32 weight, bf16 out. D=1024.
// ---------------------------------------------------------------------------
__global__ __launch_bounds__(256) void rmsnorm_k(
    const float* __restrict__ X, const float* __restrict__ W,
    bf16* __restrict__ Out)
{
    const int row = blockIdx.x, tid = threadIdx.x;
    const float4 xv = *(const float4*)(X + (size_t)row * 1024 + tid * 4);
    float ss = xv.x * xv.x + xv.y * xv.y + xv.z * xv.z + xv.w * xv.w;
#pragma unroll
    for (int m = 1; m < 64; m <<= 1) ss += __shfl_xor(ss, m);
    __shared__ float red[4];
    if ((tid & 63) == 0) red[tid >> 6] = ss;
    __syncthreads();
    float tot = red[0] + red[1] + red[2] + red[3];
    float sc = rsqrtf(tot * (1.0f / 1024.0f) + 1e-5f);
    const float4 wv = *(const float4*)(W + tid * 4);
    bf16x4 o;
    o[0] = (bf16)(xv.x * sc * wv.x);
    o[1] = (bf16)(xv.y * sc * wv.y);
    o[2] = (bf16)(xv.z * sc * wv.z);
    o[3] = (bf16)(xv.w * sc * wv.w);
    *(bf16x4*)(Out + (size_t)row * 1024 + tid * 4) = o;
}

// ---------------------------------------------------------------------------
// Q/K prep IN-PLACE in qkv (bf16): one wave per (op,b,h,s); l2norm over A=64
// then RoPE (ref signs). Each wave touches only its own 64 addresses.
// ---------------------------------------------------------------------------
__global__ __launch_bounds__(256) void qkprep_k(bf16* __restrict__ qkv)
{
    int wid  = blockIdx.x * 4 + (threadIdx.x >> 6);
    int lane = threadIdx.x & 63;
    int s = wid & 1023, h = (wid >> 10) & 15, b = (wid >> 14) & 1, op = wid >> 15;
    bf16* addr = qkv + ((size_t)(b * 1024 + s)) * 3072 + op * 1024 + h * 64 + lane;
    float v = (float)*addr;
    float ss = v * v;
#pragma unroll
    for (int m = 1; m < 64; m <<= 1) ss += __shfl_xor(ss, m);
    v /= fmaxf(sqrtf(ss), 1e-5f);
    int j = lane & 31;
    float inv = __expf(-(float)j * 0.2878231366242557f);  // ln(1e4)/32
    float f = (float)s * inv;
    float cs = cosf(f), sn = sinf(f);
    float partner = __shfl_xor(v, 32);
    float o = (lane < 32) ? (v * cs + partner * sn) : (v * cs - partner * sn);
    *addr = (bf16)o;
}

// ---------------------------------------------------------------------------
// Flash attention. Q/K/V from qkv bf16 (post-rope). Block=(qtile64,h,b),
// 4 waves x 16 q-rows, K-tiles of 32. mask = same | (causal & kv_ok & doc).
// ---------------------------------------------------------------------------
__global__ __launch_bounds__(256) void attn_k(
    const bf16* __restrict__ qkv, const int* __restrict__ doc,
    bf16* __restrict__ attnb)
{
    const int qt = blockIdx.x, h = blockIdx.y, b = blockIdx.z;
    const int tid = threadIdx.x, wave = tid >> 6, lane = tid & 63;
    const int quad = lane >> 4, l16 = lane & 15;
    const float NEG = -30000.0f;
    __shared__ __align__(16) bf16 Ks[32][72];
    __shared__ __align__(16) bf16 Vt[64][40];
    __shared__ __align__(16) bf16 Ps[4][16][40];
    __shared__ int docL[128];
    if (tid < 128) docL[tid] = doc[b * 128 + tid];

    const int qbase = qt * 64 + wave * 16;
    const bf16* qp = qkv + ((size_t)(b * 1024 + qbase + l16)) * 3072 + h * 64 + quad * 8;
    const bf16x8 qf0 = *(const bf16x8*)qp;
    const bf16x8 qf1 = *(const bf16x8*)(qp + 32);

    const f32x4 z4 = {0.f, 0.f, 0.f, 0.f};
    f32x4 O[4] = {z4, z4, z4, z4};
    float mrun[4], lrun[4];
#pragma unroll
    for (int r = 0; r < 4; r++) { mrun[r] = NEG; lrun[r] = 0.f; }

    const int ktend = (qt + 1) * 64;  // keys beyond own q-tile always masked
    for (int kt = 0; kt < ktend; kt += 32) {
        __syncthreads();
        {
            int kk = tid >> 3, a0 = (tid & 7) << 3;
            const bf16* kvrow = qkv + ((size_t)(b * 1024 + kt + kk)) * 3072 + h * 64 + a0;
            *(bf16x8*)&Ks[kk][a0] = *(const bf16x8*)(kvrow + 1024);  // K
            bf16x8 vv = *(const bf16x8*)(kvrow + 2048);              // V
#pragma unroll
            for (int jj = 0; jj < 8; jj++) Vt[a0 + jj][kk] = vv[jj];
        }
        __syncthreads();

        f32x4 sf0 = z4, sf1 = z4;
        {
            bf16x8 k0a = *(const bf16x8*)&Ks[l16][quad * 8];
            bf16x8 k0b = *(const bf16x8*)&Ks[l16][32 + quad * 8];
            sf0 = MFMA16(qf0, k0a, sf0);
            sf0 = MFMA16(qf1, k0b, sf0);
            bf16x8 k1a = *(const bf16x8*)&Ks[16 + l16][quad * 8];
            bf16x8 k1b = *(const bf16x8*)&Ks[16 + l16][32 + quad * 8];
            sf1 = MFMA16(qf0, k1a, sf1);
            sf1 = MFMA16(qf1, k1b, sf1);
        }

        float alpha[4];
#pragma unroll
        for (int r = 0; r < 4; r++) {
            int qg = qbase + quad * 4 + r;
            int bq = qg >> 3, dq = docL[bq];
            int kg0 = kt + l16, kg1 = kt + 16 + l16;
            int bk0 = kg0 >> 3, bk1 = kg1 >> 3;
            bool ok0 = (bq == bk0) || ((bq >= bk0) && ((kg0 & 7) < 4) && (dq == docL[bk0]));
            bool ok1 = (bq == bk1) || ((bq >= bk1) && ((kg1 & 7) < 4) && (dq == docL[bk1]));
            float s0 = ok0 ? sf0[r] * 0.125f : NEG;
            float s1 = ok1 ? sf1[r] * 0.125f : NEG;
            float mr = fmaxf(s0, s1);
#pragma unroll
            for (int m = 1; m < 16; m <<= 1) mr = fmaxf(mr, __shfl_xor(mr, m));
            float mn = fmaxf(mrun[r], mr);
            alpha[r] = __expf(mrun[r] - mn);
            float p0 = __expf(s0 - mn), p1 = __expf(s1 - mn);
            float ls = p0 + p1;
#pragma unroll
            for (int m = 1; m < 16; m <<= 1) ls += __shfl_xor(ls, m);
            lrun[r] = lrun[r] * alpha[r] + ls;
            mrun[r] = mn;
            Ps[wave][quad * 4 + r][l16]      = (bf16)p0;
            Ps[wave][quad * 4 + r][16 + l16] = (bf16)p1;
        }
        __syncthreads();  // Ps C-layout writes -> A-layout reads

        bf16x8 pa = *(const bf16x8*)&Ps[wave][l16][quad * 8];
#pragma unroll
        for (int t = 0; t < 4; t++) {
            bf16x8 vf = *(const bf16x8*)&Vt[t * 16 + l16][quad * 8];
#pragma unroll
            for (int r = 0; r < 4; r++) O[t][r] *= alpha[r];
            O[t] = MFMA16(pa, vf, O[t]);
        }
    }

#pragma unroll
    for (int t = 0; t < 4; t++)
#pragma unroll
        for (int r = 0; r < 4; r++) {
            int qg = qbase + quad * 4 + r;
            float v = O[t][r] / fmaxf(lrun[r], 1e-20f);
            attnb[((size_t)(b * 1024) + qg) * 1024 + h * 64 + t * 16 + l16] = (bf16)v;
        }
}

// ---------------------------------------------------------------------------
// SwiGLU IN-PLACE on bf16 up: up[r][c] = silu(up[r][c]) * up[r][2048+c].
// ---------------------------------------------------------------------------
__global__ __launch_bounds__(256) void swiglu_k(bf16* __restrict__ up)
{
    int t = blockIdx.x * 256 + threadIdx.x;   // 1M threads, 4 elems each
    int row = t >> 9, c4 = (t & 511) * 4;
    bf16* p1 = up + (size_t)row * 4096 + c4;
    const bf16x4 u1 = *(const bf16x4*)p1;
    const bf16x4 u2 = *(const bf16x4*)(p1 + 2048);
    bf16x4 o;
#pragma unroll
    for (int j = 0; j < 4; j++) {
        float a = (float)u1[j];
        float g = a / (1.f + __expf(-a));
        o[j] = (bf16)(g * (float)u2[j]);
    }
    *(bf16x4*)p1 = o;
}

// ---------------------------------------------------------------------------
// decoder permute (bf16): t1p[b,c,k, m*64+v] = t1[b, c*4+m, k*64+v]
// ---------------------------------------------------------------------------
__global__ __launch_bounds__(256) void permute_k(
    const bf16* __restrict__ t1, bf16* __restrict__ t1p)
{
    int idx = blockIdx.x * 256 + threadIdx.x;  // 262144
    int u = idx & 255, m = u >> 6, v = u & 63;
    int orow = idx >> 8;
    int k = orow & 3, bc = orow >> 2;
    int b = bc >> 7, c = bc & 127;
    t1p[idx] = t1[((size_t)(b * 512 + c * 4 + m)) * 256 + k * 64 + v];
}

// ---------------------------------------------------------------------------
// build residual x (f32): rows c*8+{0..3} = x_input(f32), {4..7} = t2+pos(f32)
// ---------------------------------------------------------------------------
__global__ __launch_bounds__(256) void buildx_k(
    const float* __restrict__ x_input, const float* __restrict__ t2,
    const float* __restrict__ pos_emb, float* __restrict__ xres)
{
    int idx = blockIdx.x * 256 + threadIdx.x;  // 2M
    int d = idx & 1023, row = idx >> 10;
    int b = row >> 10, rr = row & 1023;
    int c = rr >> 3, e = rr & 7;
    float v;
    if (e < 4)
        v = x_input[((size_t)(b * 512 + c * 4 + e)) * 1024 + d];
    else
        v = t2[((size_t)(b * 512 + c * 4 + (e - 4))) * 1024 + d] +
            pos_emb[(e - 4) * 1024 + d];
    xres[idx] = v;
}

// ---------------------------------------------------------------------------
// final slice: out[bc, kk, d] = xres[b, c*8+4+kk, d]  (f32 out)
// ---------------------------------------------------------------------------
__global__ __launch_bounds__(256) void finalout_k(
    const float* __restrict__ xres, float* __restrict__ out)
{
    int idx = blockIdx.x * 256 + threadIdx.x;  // 1M
    int d = idx & 1023, t = idx >> 10;
    int kk = t & 3, bc = t >> 2;
    int b = bc >> 7, c = bc & 127;
    out[idx] = xres[((size_t)(b * 1024 + c * 8 + 4 + kk)) * 1024 + d];
}

// ---------------------------------------------------------------------------
// Workspace plan — 32 MB, liveness-verified:
//   [ 0, 8) MB : xres f32 (whole run; xn2 bf16 borrows [0,4) in Wo->down gap)
//   [ 8,16) MB : x1res f32 (Wo->down)   | prologue: t1 [8,8.5), t1p [8.5,9)
//   [16,28) MB : qkv bf16 (Wqkv->attn; rope in-place) | t2 f32 [16,20) prologue
//   [16,32) MB : up bf16 (Wup->down; swiglu in-place, down-gemm lda=4096)
//   [28,32) MB : xn1 bf16 (norm->Wqkv)  U  attnb bf16 (attn->Wo)
// ---------------------------------------------------------------------------
extern "C" void kernel_launch(void* const* d_in, const int* in_sizes, int n_in,
                              void* d_out, int out_size, void* d_ws, size_t ws_size,
                              hipStream_t stream)
{
    const float* x_input = (const float*)d_in[0];
    const int*   doc     = (const int*)d_in[1];
    const float* dec_w1  = (const float*)d_in[2];
    const float* dec_w2  = (const float*)d_in[3];
    const float* pos_emb = (const float*)d_in[4];
    const float* Wqkv    = (const float*)d_in[5];
    const float* Wo      = (const float*)d_in[6];
    const float* Wup     = (const float*)d_in[7];
    const float* Wdown   = (const float*)d_in[8];
    const float* anw     = (const float*)d_in[9];
    const float* fnw     = (const float*)d_in[10];
    float* out = (float*)d_out;

    char* w = (char*)d_ws;
    float* xres  = (float*)(w);                    // [0,8) MB
    bf16*  xn2   = (bf16*)(w);                     // [0,4)  (xres dead window)
    float* x1res = (float*)(w + (8u << 20));       // [8,16) MB
    bf16*  t1    = (bf16*)(w + (8u << 20));        // prologue only
    bf16*  t1p   = (bf16*)(w + (8u << 20) + (512u << 10));
    bf16*  qkv   = (bf16*)(w + (16u << 20));       // [16,28) MB
    float* t2    = (float*)(w + (16u << 20));      // [16,20) prologue only
    bf16*  up    = (bf16*)(w + (16u << 20));       // [16,32) MB
    bf16*  xn1   = (bf16*)(w + (28u << 20));       // [28,32) MB
    bf16*  attnb = (bf16*)(w + (28u << 20));       // aliases xn1

    // ---- decoder prologue ----
    gemm_bt<0, 1, 1><<<dim3(2, 8), 256, 0, stream>>>(
        x_input, dec_w1, nullptr, t1, 256, 1024, 1024);
    permute_k<<<1024, 256, 0, stream>>>(t1, t1p);
    gemm_bt<2, 0, 1><<<dim3(8, 8), 256, 0, stream>>>(
        t1p, dec_w2, nullptr, t2, 1024, 256, 256);
    buildx_k<<<8192, 256, 0, stream>>>(x_input, t2, pos_emb, xres);

    // ---- 4 transformer layers ----
    for (int li = 0; li < 4; ++li) {
        rmsnorm_k<<<2048, 256, 0, stream>>>(xres, anw + li * 1024, xn1);
        gemm_bt<0, 0, 1><<<dim3(24, 16), 256, 0, stream>>>(
            xn1, Wqkv + (size_t)li * 3072 * 1024, nullptr, qkv, 3072, 1024, 1024);
        qkprep_k<<<16384, 256, 0, stream>>>(qkv);
        attn_k<<<dim3(16, 16, 2), 256, 0, stream>>>(qkv, doc, attnb);
        gemm_bt<1, 0, 1><<<dim3(8, 16), 256, 0, stream>>>(
            attnb, Wo + (size_t)li * 1024 * 1024, xres, x1res, 1024, 1024, 1024);
        rmsnorm_k<<<2048, 256, 0, stream>>>(x1res, fnw + li * 1024, xn2);
        gemm_bt<0, 0, 1><<<dim3(32, 16), 256, 0, stream>>>(
            xn2, Wup + (size_t)li * 4096 * 1024, nullptr, up, 4096, 1024, 1024);
        swiglu_k<<<4096, 256, 0, stream>>>(up);
        gemm_bt<1, 0, 1><<<dim3(8, 16), 256, 0, stream>>>(
            up, Wdown + (size_t)li * 1024 * 2048, x1res, xres, 1024, 2048, 4096);
    }

    finalout_k<<<4096, 256, 0, stream>>>(xres, out);
}

// Round 5
// 1377.326 us; speedup vs baseline: 1.0450x; 1.0450x over previous
//
#include <hip/hip_runtime.h>
#include <hip/hip_bf16.h>

typedef __bf16 bf16;
typedef __bf16 bf16x8 __attribute__((ext_vector_type(8)));
typedef __bf16 bf16x4 __attribute__((ext_vector_type(4)));
typedef float  f32x4  __attribute__((ext_vector_type(4)));

#define MFMA16(a, b, c) __builtin_amdgcn_mfma_f32_16x16x32_bf16(a, b, c, 0, 0, 0)

// ---------------------------------------------------------------------------
// GEMM: C[M,N] = A[M,K] * B[N,K]^T.  A row stride lda (elements).
// AF32/BF32: operand f32 in global -> bf16 during LDS staging.
// EPI 0: Out=bf16.  EPI 1: Out=f32 = acc + Res.  EPI 2: Out=f32.
// TM=128: 4 waves 2x2, tile 128x128.  TM=64: 4 waves 1x4, tile 64x128
// (for small grids: doubles block count on N=1024 GEMMs).
// ---------------------------------------------------------------------------
template <int EPI, int AF32, int BF32, int TM>
__global__ __launch_bounds__(256) void gemm_bt(
    const void* __restrict__ Av, const void* __restrict__ Bv,
    const float* __restrict__ Res, void* __restrict__ Out,
    int Ntot, int Ktot, int lda)
{
    __shared__ __align__(16) bf16 As[TM][40];
    __shared__ __align__(16) bf16 Bs[128][40];
    const int tid  = threadIdx.x;
    const int wave = tid >> 6, lane = tid & 63;
    const int quad = lane >> 4, l16 = lane & 15;
    constexpr int I = 4, J = (TM == 128) ? 4 : 2;
    const int rowW = (TM == 128) ? (wave >> 1) * 64 : 0;
    const int colW = (TM == 128) ? (wave & 1) * 64 : wave * 32;
    const int rowBase = blockIdx.y * TM, colBase = blockIdx.x * 128;

    f32x4 acc[I][J];
    const f32x4 z4 = {0.f, 0.f, 0.f, 0.f};
#pragma unroll
    for (int i = 0; i < I; i++)
#pragma unroll
        for (int j = 0; j < J; j++) acc[i][j] = z4;

    for (int kt = 0; kt < Ktot; kt += 32) {
        __syncthreads();
#pragma unroll
        for (int p = 0; p < 2; p++) {
            int ch = p * 256 + tid;
            int r = ch >> 2, c8 = (ch & 3) << 3;
            if (TM == 128 || r < TM) {
                if (AF32) {
                    const float* s = (const float*)Av + (size_t)(rowBase + r) * lda + kt + c8;
                    float4 u0 = *(const float4*)s, u1 = *(const float4*)(s + 4);
                    bf16x8 t;
                    t[0]=(bf16)u0.x; t[1]=(bf16)u0.y; t[2]=(bf16)u0.z; t[3]=(bf16)u0.w;
                    t[4]=(bf16)u1.x; t[5]=(bf16)u1.y; t[6]=(bf16)u1.z; t[7]=(bf16)u1.w;
                    *(bf16x8*)&As[r][c8] = t;
                } else {
                    *(bf16x8*)&As[r][c8] =
                        *(const bf16x8*)((const bf16*)Av + (size_t)(rowBase + r) * lda + kt + c8);
                }
            }
            if (BF32) {
                const float* s = (const float*)Bv + (size_t)(colBase + r) * Ktot + kt + c8;
                float4 u0 = *(const float4*)s, u1 = *(const float4*)(s + 4);
                bf16x8 t;
                t[0]=(bf16)u0.x; t[1]=(bf16)u0.y; t[2]=(bf16)u0.z; t[3]=(bf16)u0.w;
                t[4]=(bf16)u1.x; t[5]=(bf16)u1.y; t[6]=(bf16)u1.z; t[7]=(bf16)u1.w;
                *(bf16x8*)&Bs[r][c8] = t;
            } else {
                *(bf16x8*)&Bs[r][c8] =
                    *(const bf16x8*)((const bf16*)Bv + (size_t)(colBase + r) * Ktot + kt + c8);
            }
        }
        __syncthreads();
        bf16x8 af[I], bfr[J];
#pragma unroll
        for (int i = 0; i < I; i++)
            af[i] = *(const bf16x8*)&As[rowW + i * 16 + l16][quad * 8];
#pragma unroll
        for (int j = 0; j < J; j++)
            bfr[j] = *(const bf16x8*)&Bs[colW + j * 16 + l16][quad * 8];
#pragma unroll
        for (int i = 0; i < I; i++)
#pragma unroll
            for (int j = 0; j < J; j++)
                acc[i][j] = MFMA16(af[i], bfr[j], acc[i][j]);
    }

    // C/D layout: row = quad*4 + r, col = l16 (verified m89/m91)
#pragma unroll
    for (int i = 0; i < I; i++) {
        int row0 = rowBase + rowW + i * 16 + quad * 4;
#pragma unroll
        for (int j = 0; j < J; j++) {
            int col = colBase + colW + j * 16 + l16;
#pragma unroll
            for (int r = 0; r < 4; r++) {
                size_t off = (size_t)(row0 + r) * Ntot + col;
                float v = acc[i][j][r];
                if (EPI == 0)      ((bf16*)Out)[off]  = (bf16)v;
                else if (EPI == 1) ((float*)Out)[off] = v + Res[off];
                else               ((float*)Out)[off] = v;
            }
        }
    }
}

// ---------------------------------------------------------------------------
// Fused Wup GEMM + SwiGLU: each block computes a 128row x 64col hg tile.
// B-tile stages PAIRED weight rows: Bs[r] <- Wup[(r>>6)*2048 + cb*64 + (r&63)]
// so acc j=0,1 hold u1 and j=2,3 hold u2 for the same output columns.
// hg[row][cb*64 + wn*32 + jj*16 + l16] = silu(u1)*u2.  Grid (32, 16).
// ---------------------------------------------------------------------------
__global__ __launch_bounds__(256) void gemm_up_swiglu(
    const bf16* __restrict__ A, const float* __restrict__ B,
    bf16* __restrict__ Out)
{
    __shared__ __align__(16) bf16 As[128][40];
    __shared__ __align__(16) bf16 Bs[128][40];
    const int tid  = threadIdx.x;
    const int wave = tid >> 6, lane = tid & 63;
    const int quad = lane >> 4, l16 = lane & 15;
    const int wm = wave >> 1, wn = wave & 1;
    const int rowBase = blockIdx.y * 128, cb = blockIdx.x;

    f32x4 acc[4][4];
    const f32x4 z4 = {0.f, 0.f, 0.f, 0.f};
#pragma unroll
    for (int i = 0; i < 4; i++)
#pragma unroll
        for (int j = 0; j < 4; j++) acc[i][j] = z4;

    for (int kt = 0; kt < 1024; kt += 32) {
        __syncthreads();
#pragma unroll
        for (int p = 0; p < 2; p++) {
            int ch = p * 256 + tid;
            int r = ch >> 2, c8 = (ch & 3) << 3;
            *(bf16x8*)&As[r][c8] =
                *(const bf16x8*)(A + (size_t)(rowBase + r) * 1024 + kt + c8);
            int brow = (r >> 6) * 2048 + cb * 64 + (r & 63);
            const float* s = B + (size_t)brow * 1024 + kt + c8;
            float4 u0 = *(const float4*)s, u1 = *(const float4*)(s + 4);
            bf16x8 t;
            t[0]=(bf16)u0.x; t[1]=(bf16)u0.y; t[2]=(bf16)u0.z; t[3]=(bf16)u0.w;
            t[4]=(bf16)u1.x; t[5]=(bf16)u1.y; t[6]=(bf16)u1.z; t[7]=(bf16)u1.w;
            *(bf16x8*)&Bs[r][c8] = t;
        }
        __syncthreads();
        bf16x8 af[4], bfr[4];
#pragma unroll
        for (int i = 0; i < 4; i++)
            af[i] = *(const bf16x8*)&As[wm * 64 + i * 16 + l16][quad * 8];
#pragma unroll
        for (int j = 0; j < 4; j++) {
            int brow = (j < 2) ? (wn * 32 + j * 16) : (64 + wn * 32 + (j - 2) * 16);
            bfr[j] = *(const bf16x8*)&Bs[brow + l16][quad * 8];
        }
#pragma unroll
        for (int i = 0; i < 4; i++)
#pragma unroll
            for (int j = 0; j < 4; j++)
                acc[i][j] = MFMA16(af[i], bfr[j], acc[i][j]);
    }

#pragma unroll
    for (int i = 0; i < 4; i++) {
        int row0 = rowBase + wm * 64 + i * 16 + quad * 4;
#pragma unroll
        for (int jj = 0; jj < 2; jj++) {
            int col = cb * 64 + wn * 32 + jj * 16 + l16;
#pragma unroll
            for (int r = 0; r < 4; r++) {
                float u1 = acc[i][jj][r], u2 = acc[i][jj + 2][r];
                float g = u1 / (1.f + __expf(-u1));
                Out[(size_t)(row0 + r) * 2048 + col] = (bf16)(g * u2);
            }
        }
    }
}

// ---------------------------------------------------------------------------
// RMSNorm: one row per block, f32 in + f32 weight, bf16 out. D=1024.
// ---------------------------------------------------------------------------
__global__ __launch_bounds__(256) void rmsnorm_k(
    const float* __restrict__ X, const float* __restrict__ W,
    bf16* __restrict__ Out)
{
    const int row = blockIdx.x, tid = threadIdx.x;
    const float4 xv = *(const float4*)(X + (size_t)row * 1024 + tid * 4);
    float ss = xv.x * xv.x + xv.y * xv.y + xv.z * xv.z + xv.w * xv.w;
#pragma unroll
    for (int m = 1; m < 64; m <<= 1) ss += __shfl_xor(ss, m);
    __shared__ float red[4];
    if ((tid & 63) == 0) red[tid >> 6] = ss;
    __syncthreads();
    float tot = red[0] + red[1] + red[2] + red[3];
    float sc = rsqrtf(tot * (1.0f / 1024.0f) + 1e-5f);
    const float4 wv = *(const float4*)(W + tid * 4);
    bf16x4 o;
    o[0] = (bf16)(xv.x * sc * wv.x);
    o[1] = (bf16)(xv.y * sc * wv.y);
    o[2] = (bf16)(xv.z * sc * wv.z);
    o[3] = (bf16)(xv.w * sc * wv.w);
    *(bf16x4*)(Out + (size_t)row * 1024 + tid * 4) = o;
}

// ---------------------------------------------------------------------------
// RoPE cos/sin table: tab[s*32+j] = {cos,sin}(s * theta^-(j/32)).  32768 entries.
// ---------------------------------------------------------------------------
__global__ __launch_bounds__(256) void ropetab_k(float* __restrict__ tab)
{
    int i = blockIdx.x * 256 + threadIdx.x;  // 32768
    int s = i >> 5, j = i & 31;
    float f = (float)s * __expf(-(float)j * 0.2878231366242557f);  // ln(1e4)/32
    tab[i * 2]     = cosf(f);
    tab[i * 2 + 1] = sinf(f);
}

// ---------------------------------------------------------------------------
// Q/K prep IN-PLACE in qkv: one wave per (op,b,h,s); l2norm then RoPE from
// the precomputed table.
// ---------------------------------------------------------------------------
__global__ __launch_bounds__(256) void qkprep_k(
    bf16* __restrict__ qkv, const float* __restrict__ tab)
{
    int wid  = blockIdx.x * 4 + (threadIdx.x >> 6);
    int lane = threadIdx.x & 63;
    int s = wid & 1023, h = (wid >> 10) & 15, b = (wid >> 14) & 1, op = wid >> 15;
    bf16* addr = qkv + ((size_t)(b * 1024 + s)) * 3072 + op * 1024 + h * 64 + lane;
    float v = (float)*addr;
    float ss = v * v;
#pragma unroll
    for (int m = 1; m < 64; m <<= 1) ss += __shfl_xor(ss, m);
    v /= fmaxf(sqrtf(ss), 1e-5f);
    float2 cssn = ((const float2*)tab)[(s << 5) + (lane & 31)];
    float partner = __shfl_xor(v, 32);
    float o = (lane < 32) ? (v * cssn.x + partner * cssn.y)
                          : (v * cssn.x - partner * cssn.y);
    *addr = (bf16)o;
}

// ---------------------------------------------------------------------------
// V transpose: Vt[b][h][a(64)][s(1024)] <- qkv V section.  Grid (16,16,2).
// ---------------------------------------------------------------------------
__global__ __launch_bounds__(256) void vtrans_k(
    const bf16* __restrict__ qkv, bf16* __restrict__ Vt)
{
    __shared__ __align__(16) bf16 Ls[64][72];
    const int st = blockIdx.x, h = blockIdx.y, b = blockIdx.z;
    const int tid = threadIdx.x;
#pragma unroll
    for (int p = 0; p < 2; p++) {
        int s = p * 32 + (tid >> 3), a0 = (tid & 7) << 3;
        *(bf16x8*)&Ls[s][a0] = *(const bf16x8*)(
            qkv + ((size_t)(b * 1024 + st * 64 + s)) * 3072 + 2048 + h * 64 + a0);
    }
    __syncthreads();
#pragma unroll
    for (int p = 0; p < 2; p++) {
        int a = p * 32 + (tid >> 3), s0 = (tid & 7) << 3;
        bf16x8 v;
#pragma unroll
        for (int j = 0; j < 8; j++) v[j] = Ls[s0 + j][a];
        *(bf16x8*)(Vt + (((size_t)((b * 16 + h) * 64 + a)) << 10) + st * 64 + s0) = v;
    }
}

// ---------------------------------------------------------------------------
// Flash attention, barrier-free inner loop.  Grid (16, 16, 2), 4 waves.
// Wave w of block p owns 16-row q-tile g = {p, 31-p, 32+p, 63-p}[w]
// (uniform per-block work).  K frags load direct from qkv; V frags direct
// from Vt (pre-transposed).  P C->A layout via wave-PRIVATE LDS slice
// (DS ops are in-order within a wave; no __syncthreads needed).
// Mask poison from fully-masked leading tiles is flushed by alpha=exp(-3e4-m)=0.
// ---------------------------------------------------------------------------
__global__ __launch_bounds__(256) void attn_k(
    const bf16* __restrict__ qkv, const bf16* __restrict__ Vt,
    const int* __restrict__ doc, bf16* __restrict__ attnb)
{
    const int p = blockIdx.x, h = blockIdx.y, b = blockIdx.z;
    const int tid = threadIdx.x, w = tid >> 6, lane = tid & 63;
    const int quad = lane >> 4, l16 = lane & 15;
    const float NEG = -30000.0f;
    __shared__ __align__(16) bf16 PsT[4][32][20];  // [wave][key][qrow(16)+pad]
    __shared__ int docL[128];
    if (tid < 128) docL[tid] = doc[b * 128 + tid];
    __syncthreads();

    const int g = (w == 0) ? p : (w == 1) ? 31 - p : (w == 2) ? 32 + p : 63 - p;
    const bf16* qp = qkv + ((size_t)(b * 1024 + g * 16 + l16)) * 3072 + h * 64 + quad * 8;
    const bf16x8 qf0 = *(const bf16x8*)qp;
    const bf16x8 qf1 = *(const bf16x8*)(qp + 32);
    const bf16* Kbase = qkv + ((size_t)(b * 1024)) * 3072 + 1024 + h * 64;
    const bf16* Vbase = Vt + (((size_t)((b * 16 + h) * 64)) << 10);

    const f32x4 z4 = {0.f, 0.f, 0.f, 0.f};
    f32x4 O[4] = {z4, z4, z4, z4};
    float mrun[4], lrun[4];
#pragma unroll
    for (int r = 0; r < 4; r++) { mrun[r] = NEG; lrun[r] = 0.f; }

    const int tiles = (g + 2) >> 1;  // keys beyond 16(g+1) always masked
    for (int kt = 0; kt < tiles; kt++) {
        const int k0 = kt * 32;
        const bf16* kp0 = Kbase + (size_t)(k0 + l16) * 3072 + quad * 8;
        const bf16* kp1 = kp0 + 16 * 3072;
        bf16x8 k0a = *(const bf16x8*)kp0, k0b = *(const bf16x8*)(kp0 + 32);
        bf16x8 k1a = *(const bf16x8*)kp1, k1b = *(const bf16x8*)(kp1 + 32);
        f32x4 sf0 = z4, sf1 = z4;
        sf0 = MFMA16(qf0, k0a, sf0);
        sf0 = MFMA16(qf1, k0b, sf0);
        sf1 = MFMA16(qf0, k1a, sf1);
        sf1 = MFMA16(qf1, k1b, sf1);

        float alpha[4], p0v[4], p1v[4];
#pragma unroll
        for (int r = 0; r < 4; r++) {
            int qg = g * 16 + quad * 4 + r;
            int bq = qg >> 3, dq = docL[bq];
            int kg0 = k0 + l16, kg1 = k0 + 16 + l16;
            int bk0 = kg0 >> 3, bk1 = kg1 >> 3;
            bool ok0 = (bq == bk0) || ((bq >= bk0) && ((kg0 & 7) < 4) && (dq == docL[bk0]));
            bool ok1 = (bq == bk1) || ((bq >= bk1) && ((kg1 & 7) < 4) && (dq == docL[bk1]));
            float s0 = ok0 ? sf0[r] * 0.125f : NEG;
            float s1 = ok1 ? sf1[r] * 0.125f : NEG;
            float mr = fmaxf(s0, s1);
#pragma unroll
            for (int m = 1; m < 16; m <<= 1) mr = fmaxf(mr, __shfl_xor(mr, m));
            float mn = fmaxf(mrun[r], mr);
            alpha[r] = __expf(mrun[r] - mn);
            float pp0 = __expf(s0 - mn), pp1 = __expf(s1 - mn);
            float ls = pp0 + pp1;
#pragma unroll
            for (int m = 1; m < 16; m <<= 1) ls += __shfl_xor(ls, m);
            lrun[r] = lrun[r] * alpha[r] + ls;
            mrun[r] = mn;
            p0v[r] = pp0; p1v[r] = pp1;
        }
        // transposed store: PsT[key][qrow] -> A-frag reads are 2-way-conflict-free
        bf16x4 t0, t1;
#pragma unroll
        for (int r = 0; r < 4; r++) { t0[r] = (bf16)p0v[r]; t1[r] = (bf16)p1v[r]; }
        *(bf16x4*)&PsT[w][l16][quad * 4]      = t0;
        *(bf16x4*)&PsT[w][16 + l16][quad * 4] = t1;

        bf16x8 pa;  // A[m=l16][k=quad*8+j] = PsT[quad*8+j][l16]
#pragma unroll
        for (int j = 0; j < 8; j++) pa[j] = PsT[w][quad * 8 + j][l16];

#pragma unroll
        for (int t = 0; t < 4; t++) {
            bf16x8 vf = *(const bf16x8*)(Vbase + ((size_t)(t * 16 + l16) << 10) + k0 + quad * 8);
#pragma unroll
            for (int r = 0; r < 4; r++) O[t][r] *= alpha[r];
            O[t] = MFMA16(pa, vf, O[t]);
        }
    }

#pragma unroll
    for (int t = 0; t < 4; t++)
#pragma unroll
        for (int r = 0; r < 4; r++) {
            int qg = g * 16 + quad * 4 + r;
            float v = O[t][r] / fmaxf(lrun[r], 1e-20f);
            attnb[((size_t)(b * 1024) + qg) * 1024 + h * 64 + t * 16 + l16] = (bf16)v;
        }
}

// ---------------------------------------------------------------------------
// decoder permute (bf16): t1p[b,c,k, m*64+v] = t1[b, c*4+m, k*64+v]
// ---------------------------------------------------------------------------
__global__ __launch_bounds__(256) void permute_k(
    const bf16* __restrict__ t1, bf16* __restrict__ t1p)
{
    int idx = blockIdx.x * 256 + threadIdx.x;  // 262144
    int u = idx & 255, m = u >> 6, v = u & 63;
    int orow = idx >> 8;
    int k = orow & 3, bc = orow >> 2;
    int b = bc >> 7, c = bc & 127;
    t1p[idx] = t1[((size_t)(b * 512 + c * 4 + m)) * 256 + k * 64 + v];
}

// ---------------------------------------------------------------------------
// build residual x (f32): rows c*8+{0..3} = x_input, {4..7} = t2+pos
// ---------------------------------------------------------------------------
__global__ __launch_bounds__(256) void buildx_k(
    const float* __restrict__ x_input, const float* __restrict__ t2,
    const float* __restrict__ pos_emb, float* __restrict__ xres)
{
    int idx = blockIdx.x * 256 + threadIdx.x;  // 2M
    int d = idx & 1023, row = idx >> 10;
    int b = row >> 10, rr = row & 1023;
    int c = rr >> 3, e = rr & 7;
    float v;
    if (e < 4)
        v = x_input[((size_t)(b * 512 + c * 4 + e)) * 1024 + d];
    else
        v = t2[((size_t)(b * 512 + c * 4 + (e - 4))) * 1024 + d] +
            pos_emb[(e - 4) * 1024 + d];
    xres[idx] = v;
}

// ---------------------------------------------------------------------------
// final slice: out[bc, kk, d] = xres[b, c*8+4+kk, d]  (f32 out)
// ---------------------------------------------------------------------------
__global__ __launch_bounds__(256) void finalout_k(
    const float* __restrict__ xres, float* __restrict__ out)
{
    int idx = blockIdx.x * 256 + threadIdx.x;  // 1M
    int d = idx & 1023, t = idx >> 10;
    int kk = t & 3, bc = t >> 2;
    int b = bc >> 7, c = bc & 127;
    out[idx] = xres[((size_t)(b * 1024 + c * 8 + 4 + kk)) * 1024 + d];
}

// ---------------------------------------------------------------------------
// Workspace (32 MB):
//   [ 0, 8) xres f32 (whole run)
//   [ 8,12) attnb bf16 (attn->Wo)      | prologue t1 [8,8.5) t1p [8.5,9)
//   [12,16) Vt bf16 (vtrans->attn)  U  xn2 bf16 (rmsnorm2->Wup)
//   [16,28) qkv bf16 (Wqkv->attn)   |  x1res f32 [16,24) (Wo->down, qkv dead)
//           t2 f32 [16,20) prologue
//   [24,32) hg bf16 (Wup->down)     |  xn1 bf16 [28,32) (rmsnorm1->Wqkv)
// RoPE table (256 KB) lives at the head of d_out; finalout_k overwrites last.
// ---------------------------------------------------------------------------
extern "C" void kernel_launch(void* const* d_in, const int* in_sizes, int n_in,
                              void* d_out, int out_size, void* d_ws, size_t ws_size,
                              hipStream_t stream)
{
    const float* x_input = (const float*)d_in[0];
    const int*   doc     = (const int*)d_in[1];
    const float* dec_w1  = (const float*)d_in[2];
    const float* dec_w2  = (const float*)d_in[3];
    const float* pos_emb = (const float*)d_in[4];
    const float* Wqkv    = (const float*)d_in[5];
    const float* Wo      = (const float*)d_in[6];
    const float* Wup     = (const float*)d_in[7];
    const float* Wdown   = (const float*)d_in[8];
    const float* anw     = (const float*)d_in[9];
    const float* fnw     = (const float*)d_in[10];
    float* out = (float*)d_out;

    char* w = (char*)d_ws;
    float* xres  = (float*)(w);                    // [0,8)
    bf16*  attnb = (bf16*)(w + (8u << 20));        // [8,12)
    bf16*  t1    = (bf16*)(w + (8u << 20));        // prologue only
    bf16*  t1p   = (bf16*)(w + (8u << 20) + (512u << 10));
    bf16*  Vt    = (bf16*)(w + (12u << 20));       // [12,16)
    bf16*  xn2   = (bf16*)(w + (12u << 20));       // aliases Vt (disjoint liveness)
    bf16*  qkv   = (bf16*)(w + (16u << 20));       // [16,28)
    float* t2    = (float*)(w + (16u << 20));      // [16,20) prologue only
    float* x1res = (float*)(w + (16u << 20));      // [16,24) (qkv dead post-attn)
    bf16*  hg    = (bf16*)(w + (24u << 20));       // [24,32)
    bf16*  xn1   = (bf16*)(w + (28u << 20));       // [28,32)
    float* rtab  = out;                            // 256 KB scratch in d_out

    // ---- prologue ----
    ropetab_k<<<128, 256, 0, stream>>>(rtab);
    gemm_bt<0, 1, 1, 64><<<dim3(2, 16), 256, 0, stream>>>(
        x_input, dec_w1, nullptr, t1, 256, 1024, 1024);
    permute_k<<<1024, 256, 0, stream>>>(t1, t1p);
    gemm_bt<2, 0, 1, 64><<<dim3(8, 16), 256, 0, stream>>>(
        t1p, dec_w2, nullptr, t2, 1024, 256, 256);
    buildx_k<<<8192, 256, 0, stream>>>(x_input, t2, pos_emb, xres);

    // ---- 4 transformer layers ----
    for (int li = 0; li < 4; ++li) {
        rmsnorm_k<<<2048, 256, 0, stream>>>(xres, anw + li * 1024, xn1);
        gemm_bt<0, 0, 1, 128><<<dim3(24, 16), 256, 0, stream>>>(
            xn1, Wqkv + (size_t)li * 3072 * 1024, nullptr, qkv, 3072, 1024, 1024);
        qkprep_k<<<16384, 256, 0, stream>>>(qkv, rtab);
        vtrans_k<<<dim3(16, 16, 2), 256, 0, stream>>>(qkv, Vt);
        attn_k<<<dim3(16, 16, 2), 256, 0, stream>>>(qkv, Vt, doc, attnb);
        gemm_bt<1, 0, 1, 64><<<dim3(8, 32), 256, 0, stream>>>(
            attnb, Wo + (size_t)li * 1024 * 1024, xres, x1res, 1024, 1024, 1024);
        rmsnorm_k<<<2048, 256, 0, stream>>>(x1res, fnw + li * 1024, xn2);
        gemm_up_swiglu<<<dim3(32, 16), 256, 0, stream>>>(
            xn2, Wup + (size_t)li * 4096 * 1024, hg);
        gemm_bt<1, 0, 1, 64><<<dim3(8, 32), 256, 0, stream>>>(
            hg, Wdown + (size_t)li * 1024 * 2048, x1res, xres, 1024, 2048, 2048);
    }

    finalout_k<<<4096, 256, 0, stream>>>(xres, out);
}

// Round 6
// 1119.072 us; speedup vs baseline: 1.2861x; 1.2308x over previous
//
#include <hip/hip_runtime.h>
#include <hip/hip_bf16.h>

typedef __bf16 bf16;
typedef __bf16 bf16x8 __attribute__((ext_vector_type(8)));
typedef __bf16 bf16x4 __attribute__((ext_vector_type(4)));
typedef float  f32x4  __attribute__((ext_vector_type(4)));

#define MFMA16(a, b, c) __builtin_amdgcn_mfma_f32_16x16x32_bf16(a, b, c, 0, 0, 0)

// ---------------------------------------------------------------------------
// Pipelined GEMM: C[M,N] = A[M,K] * B[N,K]^T.  A row stride lda.
// Double-buffered LDS + register prefetch: one barrier per K-iter; global
// loads for tile k+1 in flight while tile k computes.
// AF32/BF32: operand f32 in global -> bf16 at LDS-store time.
// EPI 0: bf16 out.  EPI 1: f32 out = acc + Res.  EPI 2: f32 out.
// (TM,TN) in {(128,128), (64,128), (64,64)}; 256 threads.
// ---------------------------------------------------------------------------
template <int EPI, int AF32, int BF32, int TM, int TN>
__global__ __launch_bounds__(256) void gemm_bt(
    const void* __restrict__ Av, const void* __restrict__ Bv,
    const float* __restrict__ Res, void* __restrict__ Out,
    int Ntot, int Ktot, int lda)
{
    constexpr int PA = TM / 64, PB = TN / 64;
    constexpr int WN = (TN == 128) ? ((TM == 128) ? 2 : 4) : 2;
    constexpr int WM = 4 / WN;
    constexpr int I = TM / (WM * 16), J = TN / (WN * 16);
    __shared__ __align__(16) bf16 As[2][TM][40];
    __shared__ __align__(16) bf16 Bs[2][TN][40];
    const int tid  = threadIdx.x;
    const int wave = tid >> 6, lane = tid & 63;
    const int quad = lane >> 4, l16 = lane & 15;
    const int wm = wave / WN, wn = wave % WN;
    const int rowW = wm * (TM / WM), colW = wn * (TN / WN);
    const int rowBase = blockIdx.y * TM, colBase = blockIdx.x * TN;

    f32x4 acc[I][J];
    const f32x4 z4 = {0.f, 0.f, 0.f, 0.f};
#pragma unroll
    for (int i = 0; i < I; i++)
#pragma unroll
        for (int j = 0; j < J; j++) acc[i][j] = z4;

    float4 rAf[PA][2]; bf16x8 rAb[PA];
    float4 rBf[PB][2]; bf16x8 rBb[PB];

    auto loadTile = [&](int kt) {
#pragma unroll
        for (int p = 0; p < PA; p++) {
            int ch = p * 256 + tid, r = ch >> 2, c8 = (ch & 3) << 3;
            if (AF32) {
                const float* s = (const float*)Av + (size_t)(rowBase + r) * lda + kt + c8;
                rAf[p][0] = *(const float4*)s; rAf[p][1] = *(const float4*)(s + 4);
            } else {
                rAb[p] = *(const bf16x8*)((const bf16*)Av + (size_t)(rowBase + r) * lda + kt + c8);
            }
        }
#pragma unroll
        for (int p = 0; p < PB; p++) {
            int ch = p * 256 + tid, r = ch >> 2, c8 = (ch & 3) << 3;
            if (BF32) {
                const float* s = (const float*)Bv + (size_t)(colBase + r) * Ktot + kt + c8;
                rBf[p][0] = *(const float4*)s; rBf[p][1] = *(const float4*)(s + 4);
            } else {
                rBb[p] = *(const bf16x8*)((const bf16*)Bv + (size_t)(colBase + r) * Ktot + kt + c8);
            }
        }
    };
    auto storeTile = [&](int buf) {
#pragma unroll
        for (int p = 0; p < PA; p++) {
            int ch = p * 256 + tid, r = ch >> 2, c8 = (ch & 3) << 3;
            bf16x8 t;
            if (AF32) {
                t[0]=(bf16)rAf[p][0].x; t[1]=(bf16)rAf[p][0].y; t[2]=(bf16)rAf[p][0].z; t[3]=(bf16)rAf[p][0].w;
                t[4]=(bf16)rAf[p][1].x; t[5]=(bf16)rAf[p][1].y; t[6]=(bf16)rAf[p][1].z; t[7]=(bf16)rAf[p][1].w;
            } else t = rAb[p];
            *(bf16x8*)&As[buf][r][c8] = t;
        }
#pragma unroll
        for (int p = 0; p < PB; p++) {
            int ch = p * 256 + tid, r = ch >> 2, c8 = (ch & 3) << 3;
            bf16x8 t;
            if (BF32) {
                t[0]=(bf16)rBf[p][0].x; t[1]=(bf16)rBf[p][0].y; t[2]=(bf16)rBf[p][0].z; t[3]=(bf16)rBf[p][0].w;
                t[4]=(bf16)rBf[p][1].x; t[5]=(bf16)rBf[p][1].y; t[6]=(bf16)rBf[p][1].z; t[7]=(bf16)rBf[p][1].w;
            } else t = rBb[p];
            *(bf16x8*)&Bs[buf][r][c8] = t;
        }
    };

    loadTile(0);
    storeTile(0);
    __syncthreads();
    const int nk = Ktot >> 5;
    for (int k = 0; k < nk; k++) {
        const bool more = (k + 1) < nk;
        if (more) loadTile((k + 1) << 5);          // in flight during compute
        const int buf = k & 1;
        bf16x8 af[I], bfr[J];
#pragma unroll
        for (int i = 0; i < I; i++)
            af[i] = *(const bf16x8*)&As[buf][rowW + i * 16 + l16][quad * 8];
#pragma unroll
        for (int j = 0; j < J; j++)
            bfr[j] = *(const bf16x8*)&Bs[buf][colW + j * 16 + l16][quad * 8];
#pragma unroll
        for (int i = 0; i < I; i++)
#pragma unroll
            for (int j = 0; j < J; j++)
                acc[i][j] = MFMA16(af[i], bfr[j], acc[i][j]);
        if (more) { storeTile(buf ^ 1); __syncthreads(); }
    }

    // C/D layout: row = quad*4 + r, col = l16 (verified m89/m91)
#pragma unroll
    for (int i = 0; i < I; i++) {
        int row0 = rowBase + rowW + i * 16 + quad * 4;
#pragma unroll
        for (int j = 0; j < J; j++) {
            int col = colBase + colW + j * 16 + l16;
#pragma unroll
            for (int r = 0; r < 4; r++) {
                size_t off = (size_t)(row0 + r) * Ntot + col;
                float v = acc[i][j][r];
                if (EPI == 0)      ((bf16*)Out)[off]  = (bf16)v;
                else if (EPI == 1) ((float*)Out)[off] = v + Res[off];
                else               ((float*)Out)[off] = v;
            }
        }
    }
}

// ---------------------------------------------------------------------------
// Fused Wup GEMM + SwiGLU (pipelined): 128row x 64col hg tile per block.
// Bs rows pair u1/u2 weight rows: Bs[r] <- Wup[(r>>6)*2048 + cb*64 + (r&63)],
// acc j=0,1 -> u1, j=2,3 -> u2.  Grid (32, 16).
// ---------------------------------------------------------------------------
__global__ __launch_bounds__(256) void gemm_up_swiglu(
    const bf16* __restrict__ A, const float* __restrict__ B,
    bf16* __restrict__ Out)
{
    __shared__ __align__(16) bf16 As[2][128][40];
    __shared__ __align__(16) bf16 Bs[2][128][40];
    const int tid  = threadIdx.x;
    const int wave = tid >> 6, lane = tid & 63;
    const int quad = lane >> 4, l16 = lane & 15;
    const int wm = wave >> 1, wn = wave & 1;
    const int rowBase = blockIdx.y * 128, cb = blockIdx.x;

    f32x4 acc[4][4];
    const f32x4 z4 = {0.f, 0.f, 0.f, 0.f};
#pragma unroll
    for (int i = 0; i < 4; i++)
#pragma unroll
        for (int j = 0; j < 4; j++) acc[i][j] = z4;

    bf16x8 rA[2]; float4 rB[2][2];
    auto loadTile = [&](int kt) {
#pragma unroll
        for (int p = 0; p < 2; p++) {
            int ch = p * 256 + tid, r = ch >> 2, c8 = (ch & 3) << 3;
            rA[p] = *(const bf16x8*)(A + (size_t)(rowBase + r) * 1024 + kt + c8);
            int brow = (r >> 6) * 2048 + cb * 64 + (r & 63);
            const float* s = B + (size_t)brow * 1024 + kt + c8;
            rB[p][0] = *(const float4*)s; rB[p][1] = *(const float4*)(s + 4);
        }
    };
    auto storeTile = [&](int buf) {
#pragma unroll
        for (int p = 0; p < 2; p++) {
            int ch = p * 256 + tid, r = ch >> 2, c8 = (ch & 3) << 3;
            *(bf16x8*)&As[buf][r][c8] = rA[p];
            bf16x8 t;
            t[0]=(bf16)rB[p][0].x; t[1]=(bf16)rB[p][0].y; t[2]=(bf16)rB[p][0].z; t[3]=(bf16)rB[p][0].w;
            t[4]=(bf16)rB[p][1].x; t[5]=(bf16)rB[p][1].y; t[6]=(bf16)rB[p][1].z; t[7]=(bf16)rB[p][1].w;
            *(bf16x8*)&Bs[buf][r][c8] = t;
        }
    };

    loadTile(0);
    storeTile(0);
    __syncthreads();
    for (int k = 0; k < 32; k++) {
        const bool more = k < 31;
        if (more) loadTile((k + 1) << 5);
        const int buf = k & 1;
        bf16x8 af[4], bfr[4];
#pragma unroll
        for (int i = 0; i < 4; i++)
            af[i] = *(const bf16x8*)&As[buf][wm * 64 + i * 16 + l16][quad * 8];
#pragma unroll
        for (int j = 0; j < 4; j++) {
            int brow = (j < 2) ? (wn * 32 + j * 16) : (64 + wn * 32 + (j - 2) * 16);
            bfr[j] = *(const bf16x8*)&Bs[buf][brow + l16][quad * 8];
        }
#pragma unroll
        for (int i = 0; i < 4; i++)
#pragma unroll
            for (int j = 0; j < 4; j++)
                acc[i][j] = MFMA16(af[i], bfr[j], acc[i][j]);
        if (more) { storeTile(buf ^ 1); __syncthreads(); }
    }

#pragma unroll
    for (int i = 0; i < 4; i++) {
        int row0 = rowBase + wm * 64 + i * 16 + quad * 4;
#pragma unroll
        for (int jj = 0; jj < 2; jj++) {
            int col = cb * 64 + wn * 32 + jj * 16 + l16;
#pragma unroll
            for (int r = 0; r < 4; r++) {
                float u1 = acc[i][jj][r], u2 = acc[i][jj + 2][r];
                float g = u1 / (1.f + __expf(-u1));
                Out[(size_t)(row0 + r) * 2048 + col] = (bf16)(g * u2);
            }
        }
    }
}

// ---------------------------------------------------------------------------
// RMSNorm: one row per block, f32 in + f32 weight, bf16 out. D=1024.
// ---------------------------------------------------------------------------
__global__ __launch_bounds__(256) void rmsnorm_k(
    const float* __restrict__ X, const float* __restrict__ W,
    bf16* __restrict__ Out)
{
    const int row = blockIdx.x, tid = threadIdx.x;
    const float4 xv = *(const float4*)(X + (size_t)row * 1024 + tid * 4);
    float ss = xv.x * xv.x + xv.y * xv.y + xv.z * xv.z + xv.w * xv.w;
#pragma unroll
    for (int m = 1; m < 64; m <<= 1) ss += __shfl_xor(ss, m);
    __shared__ float red[4];
    if ((tid & 63) == 0) red[tid >> 6] = ss;
    __syncthreads();
    float tot = red[0] + red[1] + red[2] + red[3];
    float sc = rsqrtf(tot * (1.0f / 1024.0f) + 1e-5f);
    const float4 wv = *(const float4*)(W + tid * 4);
    bf16x4 o;
    o[0] = (bf16)(xv.x * sc * wv.x);
    o[1] = (bf16)(xv.y * sc * wv.y);
    o[2] = (bf16)(xv.z * sc * wv.z);
    o[3] = (bf16)(xv.w * sc * wv.w);
    *(bf16x4*)(Out + (size_t)row * 1024 + tid * 4) = o;
}

// ---------------------------------------------------------------------------
// RoPE cos/sin table: tab[s*32+j] = {cos,sin}(s * theta^-(j/32)).
// ---------------------------------------------------------------------------
__global__ __launch_bounds__(256) void ropetab_k(float* __restrict__ tab)
{
    int i = blockIdx.x * 256 + threadIdx.x;  // 32768
    int s = i >> 5, j = i & 31;
    float f = (float)s * __expf(-(float)j * 0.2878231366242557f);  // ln(1e4)/32
    tab[i * 2]     = cosf(f);
    tab[i * 2 + 1] = sinf(f);
}

// ---------------------------------------------------------------------------
// Q/K prep IN-PLACE in qkv: one wave per (op,b,h,s); l2norm then RoPE.
// ---------------------------------------------------------------------------
__global__ __launch_bounds__(256) void qkprep_k(
    bf16* __restrict__ qkv, const float* __restrict__ tab)
{
    int wid  = blockIdx.x * 4 + (threadIdx.x >> 6);
    int lane = threadIdx.x & 63;
    int s = wid & 1023, h = (wid >> 10) & 15, b = (wid >> 14) & 1, op = wid >> 15;
    bf16* addr = qkv + ((size_t)(b * 1024 + s)) * 3072 + op * 1024 + h * 64 + lane;
    float v = (float)*addr;
    float ss = v * v;
#pragma unroll
    for (int m = 1; m < 64; m <<= 1) ss += __shfl_xor(ss, m);
    v /= fmaxf(sqrtf(ss), 1e-5f);
    float2 cssn = ((const float2*)tab)[(s << 5) + (lane & 31)];
    float partner = __shfl_xor(v, 32);
    float o = (lane < 32) ? (v * cssn.x + partner * cssn.y)
                          : (v * cssn.x - partner * cssn.y);
    *addr = (bf16)o;
}

// ---------------------------------------------------------------------------
// V transpose: Vt[b][h][a(64)][s(1024)] <- qkv V section.  Grid (16,16,2).
// ---------------------------------------------------------------------------
__global__ __launch_bounds__(256) void vtrans_k(
    const bf16* __restrict__ qkv, bf16* __restrict__ Vt)
{
    __shared__ __align__(16) bf16 Ls[64][72];
    const int st = blockIdx.x, h = blockIdx.y, b = blockIdx.z;
    const int tid = threadIdx.x;
#pragma unroll
    for (int p = 0; p < 2; p++) {
        int s = p * 32 + (tid >> 3), a0 = (tid & 7) << 3;
        *(bf16x8*)&Ls[s][a0] = *(const bf16x8*)(
            qkv + ((size_t)(b * 1024 + st * 64 + s)) * 3072 + 2048 + h * 64 + a0);
    }
    __syncthreads();
#pragma unroll
    for (int p = 0; p < 2; p++) {
        int a = p * 32 + (tid >> 3), s0 = (tid & 7) << 3;
        bf16x8 v;
#pragma unroll
        for (int j = 0; j < 8; j++) v[j] = Ls[s0 + j][a];
        *(bf16x8*)(Vt + (((size_t)((b * 16 + h) * 64 + a)) << 10) + st * 64 + s0) = v;
    }
}

// ---------------------------------------------------------------------------
// Flash attention, barrier-free inner loop (round-5 design, unchanged).
// ---------------------------------------------------------------------------
__global__ __launch_bounds__(256) void attn_k(
    const bf16* __restrict__ qkv, const bf16* __restrict__ Vt,
    const int* __restrict__ doc, bf16* __restrict__ attnb)
{
    const int p = blockIdx.x, h = blockIdx.y, b = blockIdx.z;
    const int tid = threadIdx.x, w = tid >> 6, lane = tid & 63;
    const int quad = lane >> 4, l16 = lane & 15;
    const float NEG = -30000.0f;
    __shared__ __align__(16) bf16 PsT[4][32][20];
    __shared__ int docL[128];
    if (tid < 128) docL[tid] = doc[b * 128 + tid];
    __syncthreads();

    const int g = (w == 0) ? p : (w == 1) ? 31 - p : (w == 2) ? 32 + p : 63 - p;
    const bf16* qp = qkv + ((size_t)(b * 1024 + g * 16 + l16)) * 3072 + h * 64 + quad * 8;
    const bf16x8 qf0 = *(const bf16x8*)qp;
    const bf16x8 qf1 = *(const bf16x8*)(qp + 32);
    const bf16* Kbase = qkv + ((size_t)(b * 1024)) * 3072 + 1024 + h * 64;
    const bf16* Vbase = Vt + (((size_t)((b * 16 + h) * 64)) << 10);

    const f32x4 z4 = {0.f, 0.f, 0.f, 0.f};
    f32x4 O[4] = {z4, z4, z4, z4};
    float mrun[4], lrun[4];
#pragma unroll
    for (int r = 0; r < 4; r++) { mrun[r] = NEG; lrun[r] = 0.f; }

    const int tiles = (g + 2) >> 1;
    for (int kt = 0; kt < tiles; kt++) {
        const int k0 = kt * 32;
        const bf16* kp0 = Kbase + (size_t)(k0 + l16) * 3072 + quad * 8;
        const bf16* kp1 = kp0 + 16 * 3072;
        bf16x8 k0a = *(const bf16x8*)kp0, k0b = *(const bf16x8*)(kp0 + 32);
        bf16x8 k1a = *(const bf16x8*)kp1, k1b = *(const bf16x8*)(kp1 + 32);
        f32x4 sf0 = z4, sf1 = z4;
        sf0 = MFMA16(qf0, k0a, sf0);
        sf0 = MFMA16(qf1, k0b, sf0);
        sf1 = MFMA16(qf0, k1a, sf1);
        sf1 = MFMA16(qf1, k1b, sf1);

        float alpha[4], p0v[4], p1v[4];
#pragma unroll
        for (int r = 0; r < 4; r++) {
            int qg = g * 16 + quad * 4 + r;
            int bq = qg >> 3, dq = docL[bq];
            int kg0 = k0 + l16, kg1 = k0 + 16 + l16;
            int bk0 = kg0 >> 3, bk1 = kg1 >> 3;
            bool ok0 = (bq == bk0) || ((bq >= bk0) && ((kg0 & 7) < 4) && (dq == docL[bk0]));
            bool ok1 = (bq == bk1) || ((bq >= bk1) && ((kg1 & 7) < 4) && (dq == docL[bk1]));
            float s0 = ok0 ? sf0[r] * 0.125f : NEG;
            float s1 = ok1 ? sf1[r] * 0.125f : NEG;
            float mr = fmaxf(s0, s1);
#pragma unroll
            for (int m = 1; m < 16; m <<= 1) mr = fmaxf(mr, __shfl_xor(mr, m));
            float mn = fmaxf(mrun[r], mr);
            alpha[r] = __expf(mrun[r] - mn);
            float pp0 = __expf(s0 - mn), pp1 = __expf(s1 - mn);
            float ls = pp0 + pp1;
#pragma unroll
            for (int m = 1; m < 16; m <<= 1) ls += __shfl_xor(ls, m);
            lrun[r] = lrun[r] * alpha[r] + ls;
            mrun[r] = mn;
            p0v[r] = pp0; p1v[r] = pp1;
        }
        bf16x4 t0, t1;
#pragma unroll
        for (int r = 0; r < 4; r++) { t0[r] = (bf16)p0v[r]; t1[r] = (bf16)p1v[r]; }
        *(bf16x4*)&PsT[w][l16][quad * 4]      = t0;
        *(bf16x4*)&PsT[w][16 + l16][quad * 4] = t1;

        bf16x8 pa;
#pragma unroll
        for (int j = 0; j < 8; j++) pa[j] = PsT[w][quad * 8 + j][l16];

#pragma unroll
        for (int t = 0; t < 4; t++) {
            bf16x8 vf = *(const bf16x8*)(Vbase + ((size_t)(t * 16 + l16) << 10) + k0 + quad * 8);
#pragma unroll
            for (int r = 0; r < 4; r++) O[t][r] *= alpha[r];
            O[t] = MFMA16(pa, vf, O[t]);
        }
    }

#pragma unroll
    for (int t = 0; t < 4; t++)
#pragma unroll
        for (int r = 0; r < 4; r++) {
            int qg = g * 16 + quad * 4 + r;
            float v = O[t][r] / fmaxf(lrun[r], 1e-20f);
            attnb[((size_t)(b * 1024) + qg) * 1024 + h * 64 + t * 16 + l16] = (bf16)v;
        }
}

// ---------------------------------------------------------------------------
__global__ __launch_bounds__(256) void permute_k(
    const bf16* __restrict__ t1, bf16* __restrict__ t1p)
{
    int idx = blockIdx.x * 256 + threadIdx.x;  // 262144
    int u = idx & 255, m = u >> 6, v = u & 63;
    int orow = idx >> 8;
    int k = orow & 3, bc = orow >> 2;
    int b = bc >> 7, c = bc & 127;
    t1p[idx] = t1[((size_t)(b * 512 + c * 4 + m)) * 256 + k * 64 + v];
}

__global__ __launch_bounds__(256) void buildx_k(
    const float* __restrict__ x_input, const float* __restrict__ t2,
    const float* __restrict__ pos_emb, float* __restrict__ xres)
{
    int idx = blockIdx.x * 256 + threadIdx.x;  // 2M
    int d = idx & 1023, row = idx >> 10;
    int b = row >> 10, rr = row & 1023;
    int c = rr >> 3, e = rr & 7;
    float v;
    if (e < 4)
        v = x_input[((size_t)(b * 512 + c * 4 + e)) * 1024 + d];
    else
        v = t2[((size_t)(b * 512 + c * 4 + (e - 4))) * 1024 + d] +
            pos_emb[(e - 4) * 1024 + d];
    xres[idx] = v;
}

__global__ __launch_bounds__(256) void finalout_k(
    const float* __restrict__ xres, float* __restrict__ out)
{
    int idx = blockIdx.x * 256 + threadIdx.x;  // 1M
    int d = idx & 1023, t = idx >> 10;
    int kk = t & 3, bc = t >> 2;
    int b = bc >> 7, c = bc & 127;
    out[idx] = xres[((size_t)(b * 1024 + c * 8 + 4 + kk)) * 1024 + d];
}

// ---------------------------------------------------------------------------
// Workspace (32 MB): same liveness plan as round 5.
// ---------------------------------------------------------------------------
extern "C" void kernel_launch(void* const* d_in, const int* in_sizes, int n_in,
                              void* d_out, int out_size, void* d_ws, size_t ws_size,
                              hipStream_t stream)
{
    const float* x_input = (const float*)d_in[0];
    const int*   doc     = (const int*)d_in[1];
    const float* dec_w1  = (const float*)d_in[2];
    const float* dec_w2  = (const float*)d_in[3];
    const float* pos_emb = (const float*)d_in[4];
    const float* Wqkv    = (const float*)d_in[5];
    const float* Wo      = (const float*)d_in[6];
    const float* Wup     = (const float*)d_in[7];
    const float* Wdown   = (const float*)d_in[8];
    const float* anw     = (const float*)d_in[9];
    const float* fnw     = (const float*)d_in[10];
    float* out = (float*)d_out;

    char* w = (char*)d_ws;
    float* xres  = (float*)(w);                    // [0,8)
    bf16*  attnb = (bf16*)(w + (8u << 20));        // [8,12)
    bf16*  t1    = (bf16*)(w + (8u << 20));        // prologue only
    bf16*  t1p   = (bf16*)(w + (8u << 20) + (512u << 10));
    bf16*  Vt    = (bf16*)(w + (12u << 20));       // [12,16)
    bf16*  xn2   = (bf16*)(w + (12u << 20));       // aliases Vt
    bf16*  qkv   = (bf16*)(w + (16u << 20));       // [16,28)
    float* t2    = (float*)(w + (16u << 20));      // [16,20) prologue only
    float* x1res = (float*)(w + (16u << 20));      // [16,24) (qkv dead post-attn)
    bf16*  hg    = (bf16*)(w + (24u << 20));       // [24,32)
    bf16*  xn1   = (bf16*)(w + (28u << 20));       // [28,32)
    float* rtab  = out;                            // 256 KB scratch in d_out

    // ---- prologue ----
    ropetab_k<<<128, 256, 0, stream>>>(rtab);
    gemm_bt<0, 1, 1, 64, 64><<<dim3(4, 16), 256, 0, stream>>>(
        x_input, dec_w1, nullptr, t1, 256, 1024, 1024);
    permute_k<<<1024, 256, 0, stream>>>(t1, t1p);
    gemm_bt<2, 0, 1, 64, 64><<<dim3(16, 16), 256, 0, stream>>>(
        t1p, dec_w2, nullptr, t2, 1024, 256, 256);
    buildx_k<<<8192, 256, 0, stream>>>(x_input, t2, pos_emb, xres);

    // ---- 4 transformer layers ----
    for (int li = 0; li < 4; ++li) {
        rmsnorm_k<<<2048, 256, 0, stream>>>(xres, anw + li * 1024, xn1);
        gemm_bt<0, 0, 1, 128, 128><<<dim3(24, 16), 256, 0, stream>>>(
            xn1, Wqkv + (size_t)li * 3072 * 1024, nullptr, qkv, 3072, 1024, 1024);
        qkprep_k<<<16384, 256, 0, stream>>>(qkv, rtab);
        vtrans_k<<<dim3(16, 16, 2), 256, 0, stream>>>(qkv, Vt);
        attn_k<<<dim3(16, 16, 2), 256, 0, stream>>>(qkv, Vt, doc, attnb);
        gemm_bt<1, 0, 1, 64, 64><<<dim3(16, 32), 256, 0, stream>>>(
            attnb, Wo + (size_t)li * 1024 * 1024, xres, x1res, 1024, 1024, 1024);
        rmsnorm_k<<<2048, 256, 0, stream>>>(x1res, fnw + li * 1024, xn2);
        gemm_up_swiglu<<<dim3(32, 16), 256, 0, stream>>>(
            xn2, Wup + (size_t)li * 4096 * 1024, hg);
        gemm_bt<1, 0, 1, 64, 64><<<dim3(16, 32), 256, 0, stream>>>(
            hg, Wdown + (size_t)li * 1024 * 2048, x1res, xres, 1024, 2048, 2048);
    }

    finalout_k<<<4096, 256, 0, stream>>>(xres, out);
}

// Round 7
// 1063.804 us; speedup vs baseline: 1.3529x; 1.0520x over previous
//
#include <hip/hip_runtime.h>
#include <hip/hip_bf16.h>

typedef __bf16 bf16;
typedef __bf16 bf16x8 __attribute__((ext_vector_type(8)));
typedef __bf16 bf16x4 __attribute__((ext_vector_type(4)));
typedef float  f32x4  __attribute__((ext_vector_type(4)));

#define MFMA16(a, b, c) __builtin_amdgcn_mfma_f32_16x16x32_bf16(a, b, c, 0, 0, 0)

// ---------------------------------------------------------------------------
// Pipelined GEMM: C[M,N] = A[M,K] * B[N,K]^T.  A row stride lda.
// Double-buffered LDS + register prefetch; one barrier per K-iter.
// AF32/BF32: operand f32 in global -> bf16 at LDS-store time.
// EPI 0: bf16 out.  EPI 1: f32 out = acc + Res.  EPI 2: f32 out.
// ---------------------------------------------------------------------------
template <int EPI, int AF32, int BF32, int TM, int TN>
__global__ __launch_bounds__(256) void gemm_bt(
    const void* __restrict__ Av, const void* __restrict__ Bv,
    const float* __restrict__ Res, void* __restrict__ Out,
    int Ntot, int Ktot, int lda)
{
    constexpr int PA = TM / 64, PB = TN / 64;
    constexpr int WN = (TN == 128) ? ((TM == 128) ? 2 : 4) : 2;
    constexpr int WM = 4 / WN;
    constexpr int I = TM / (WM * 16), J = TN / (WN * 16);
    __shared__ __align__(16) bf16 As[2][TM][40];
    __shared__ __align__(16) bf16 Bs[2][TN][40];
    const int tid  = threadIdx.x;
    const int wave = tid >> 6, lane = tid & 63;
    const int quad = lane >> 4, l16 = lane & 15;
    const int wm = wave / WN, wn = wave % WN;
    const int rowW = wm * (TM / WM), colW = wn * (TN / WN);
    const int rowBase = blockIdx.y * TM, colBase = blockIdx.x * TN;

    f32x4 acc[I][J];
    const f32x4 z4 = {0.f, 0.f, 0.f, 0.f};
#pragma unroll
    for (int i = 0; i < I; i++)
#pragma unroll
        for (int j = 0; j < J; j++) acc[i][j] = z4;

    float4 rAf[PA][2]; bf16x8 rAb[PA];
    float4 rBf[PB][2]; bf16x8 rBb[PB];

    auto loadTile = [&](int kt) {
#pragma unroll
        for (int p = 0; p < PA; p++) {
            int ch = p * 256 + tid, r = ch >> 2, c8 = (ch & 3) << 3;
            if (AF32) {
                const float* s = (const float*)Av + (size_t)(rowBase + r) * lda + kt + c8;
                rAf[p][0] = *(const float4*)s; rAf[p][1] = *(const float4*)(s + 4);
            } else {
                rAb[p] = *(const bf16x8*)((const bf16*)Av + (size_t)(rowBase + r) * lda + kt + c8);
            }
        }
#pragma unroll
        for (int p = 0; p < PB; p++) {
            int ch = p * 256 + tid, r = ch >> 2, c8 = (ch & 3) << 3;
            if (BF32) {
                const float* s = (const float*)Bv + (size_t)(colBase + r) * Ktot + kt + c8;
                rBf[p][0] = *(const float4*)s; rBf[p][1] = *(const float4*)(s + 4);
            } else {
                rBb[p] = *(const bf16x8*)((const bf16*)Bv + (size_t)(colBase + r) * Ktot + kt + c8);
            }
        }
    };
    auto storeTile = [&](int buf) {
#pragma unroll
        for (int p = 0; p < PA; p++) {
            int ch = p * 256 + tid, r = ch >> 2, c8 = (ch & 3) << 3;
            bf16x8 t;
            if (AF32) {
                t[0]=(bf16)rAf[p][0].x; t[1]=(bf16)rAf[p][0].y; t[2]=(bf16)rAf[p][0].z; t[3]=(bf16)rAf[p][0].w;
                t[4]=(bf16)rAf[p][1].x; t[5]=(bf16)rAf[p][1].y; t[6]=(bf16)rAf[p][1].z; t[7]=(bf16)rAf[p][1].w;
            } else t = rAb[p];
            *(bf16x8*)&As[buf][r][c8] = t;
        }
#pragma unroll
        for (int p = 0; p < PB; p++) {
            int ch = p * 256 + tid, r = ch >> 2, c8 = (ch & 3) << 3;
            bf16x8 t;
            if (BF32) {
                t[0]=(bf16)rBf[p][0].x; t[1]=(bf16)rBf[p][0].y; t[2]=(bf16)rBf[p][0].z; t[3]=(bf16)rBf[p][0].w;
                t[4]=(bf16)rBf[p][1].x; t[5]=(bf16)rBf[p][1].y; t[6]=(bf16)rBf[p][1].z; t[7]=(bf16)rBf[p][1].w;
            } else t = rBb[p];
            *(bf16x8*)&Bs[buf][r][c8] = t;
        }
    };

    loadTile(0);
    storeTile(0);
    __syncthreads();
    const int nk = Ktot >> 5;
    for (int k = 0; k < nk; k++) {
        const bool more = (k + 1) < nk;
        if (more) loadTile((k + 1) << 5);
        const int buf = k & 1;
        bf16x8 af[I], bfr[J];
#pragma unroll
        for (int i = 0; i < I; i++)
            af[i] = *(const bf16x8*)&As[buf][rowW + i * 16 + l16][quad * 8];
#pragma unroll
        for (int j = 0; j < J; j++)
            bfr[j] = *(const bf16x8*)&Bs[buf][colW + j * 16 + l16][quad * 8];
#pragma unroll
        for (int i = 0; i < I; i++)
#pragma unroll
            for (int j = 0; j < J; j++)
                acc[i][j] = MFMA16(af[i], bfr[j], acc[i][j]);
        if (more) { storeTile(buf ^ 1); __syncthreads(); }
    }

    // C/D layout: row = quad*4 + r, col = l16 (verified m89/m91)
#pragma unroll
    for (int i = 0; i < I; i++) {
        int row0 = rowBase + rowW + i * 16 + quad * 4;
#pragma unroll
        for (int j = 0; j < J; j++) {
            int col = colBase + colW + j * 16 + l16;
#pragma unroll
            for (int r = 0; r < 4; r++) {
                size_t off = (size_t)(row0 + r) * Ntot + col;
                float v = acc[i][j][r];
                if (EPI == 0)      ((bf16*)Out)[off]  = (bf16)v;
                else if (EPI == 1) ((float*)Out)[off] = v + Res[off];
                else               ((float*)Out)[off] = v;
            }
        }
    }
}

// ---------------------------------------------------------------------------
// Fused Wup GEMM + SwiGLU (pipelined): 128row x 64col hg tile per block.
// ---------------------------------------------------------------------------
__global__ __launch_bounds__(256) void gemm_up_swiglu(
    const bf16* __restrict__ A, const float* __restrict__ B,
    bf16* __restrict__ Out)
{
    __shared__ __align__(16) bf16 As[2][128][40];
    __shared__ __align__(16) bf16 Bs[2][128][40];
    const int tid  = threadIdx.x;
    const int wave = tid >> 6, lane = tid & 63;
    const int quad = lane >> 4, l16 = lane & 15;
    const int wm = wave >> 1, wn = wave & 1;
    const int rowBase = blockIdx.y * 128, cb = blockIdx.x;

    f32x4 acc[4][4];
    const f32x4 z4 = {0.f, 0.f, 0.f, 0.f};
#pragma unroll
    for (int i = 0; i < 4; i++)
#pragma unroll
        for (int j = 0; j < 4; j++) acc[i][j] = z4;

    bf16x8 rA[2]; float4 rB[2][2];
    auto loadTile = [&](int kt) {
#pragma unroll
        for (int p = 0; p < 2; p++) {
            int ch = p * 256 + tid, r = ch >> 2, c8 = (ch & 3) << 3;
            rA[p] = *(const bf16x8*)(A + (size_t)(rowBase + r) * 1024 + kt + c8);
            int brow = (r >> 6) * 2048 + cb * 64 + (r & 63);
            const float* s = B + (size_t)brow * 1024 + kt + c8;
            rB[p][0] = *(const float4*)s; rB[p][1] = *(const float4*)(s + 4);
        }
    };
    auto storeTile = [&](int buf) {
#pragma unroll
        for (int p = 0; p < 2; p++) {
            int ch = p * 256 + tid, r = ch >> 2, c8 = (ch & 3) << 3;
            *(bf16x8*)&As[buf][r][c8] = rA[p];
            bf16x8 t;
            t[0]=(bf16)rB[p][0].x; t[1]=(bf16)rB[p][0].y; t[2]=(bf16)rB[p][0].z; t[3]=(bf16)rB[p][0].w;
            t[4]=(bf16)rB[p][1].x; t[5]=(bf16)rB[p][1].y; t[6]=(bf16)rB[p][1].z; t[7]=(bf16)rB[p][1].w;
            *(bf16x8*)&Bs[buf][r][c8] = t;
        }
    };

    loadTile(0);
    storeTile(0);
    __syncthreads();
    for (int k = 0; k < 32; k++) {
        const bool more = k < 31;
        if (more) loadTile((k + 1) << 5);
        const int buf = k & 1;
        bf16x8 af[4], bfr[4];
#pragma unroll
        for (int i = 0; i < 4; i++)
            af[i] = *(const bf16x8*)&As[buf][wm * 64 + i * 16 + l16][quad * 8];
#pragma unroll
        for (int j = 0; j < 4; j++) {
            int brow = (j < 2) ? (wn * 32 + j * 16) : (64 + wn * 32 + (j - 2) * 16);
            bfr[j] = *(const bf16x8*)&Bs[buf][brow + l16][quad * 8];
        }
#pragma unroll
        for (int i = 0; i < 4; i++)
#pragma unroll
            for (int j = 0; j < 4; j++)
                acc[i][j] = MFMA16(af[i], bfr[j], acc[i][j]);
        if (more) { storeTile(buf ^ 1); __syncthreads(); }
    }

#pragma unroll
    for (int i = 0; i < 4; i++) {
        int row0 = rowBase + wm * 64 + i * 16 + quad * 4;
#pragma unroll
        for (int jj = 0; jj < 2; jj++) {
            int col = cb * 64 + wn * 32 + jj * 16 + l16;
#pragma unroll
            for (int r = 0; r < 4; r++) {
                float u1 = acc[i][jj][r], u2 = acc[i][jj + 2][r];
                float g = u1 / (1.f + __expf(-u1));
                Out[(size_t)(row0 + r) * 2048 + col] = (bf16)(g * u2);
            }
        }
    }
}

// ---------------------------------------------------------------------------
__global__ __launch_bounds__(256) void rmsnorm_k(
    const float* __restrict__ X, const float* __restrict__ W,
    bf16* __restrict__ Out)
{
    const int row = blockIdx.x, tid = threadIdx.x;
    const float4 xv = *(const float4*)(X + (size_t)row * 1024 + tid * 4);
    float ss = xv.x * xv.x + xv.y * xv.y + xv.z * xv.z + xv.w * xv.w;
#pragma unroll
    for (int m = 1; m < 64; m <<= 1) ss += __shfl_xor(ss, m);
    __shared__ float red[4];
    if ((tid & 63) == 0) red[tid >> 6] = ss;
    __syncthreads();
    float tot = red[0] + red[1] + red[2] + red[3];
    float sc = rsqrtf(tot * (1.0f / 1024.0f) + 1e-5f);
    const float4 wv = *(const float4*)(W + tid * 4);
    bf16x4 o;
    o[0] = (bf16)(xv.x * sc * wv.x);
    o[1] = (bf16)(xv.y * sc * wv.y);
    o[2] = (bf16)(xv.z * sc * wv.z);
    o[3] = (bf16)(xv.w * sc * wv.w);
    *(bf16x4*)(Out + (size_t)row * 1024 + tid * 4) = o;
}

// ---------------------------------------------------------------------------
__global__ __launch_bounds__(256) void ropetab_k(float* __restrict__ tab)
{
    int i = blockIdx.x * 256 + threadIdx.x;  // 32768
    int s = i >> 5, j = i & 31;
    float f = (float)s * __expf(-(float)j * 0.2878231366242557f);  // ln(1e4)/32
    tab[i * 2]     = cosf(f);
    tab[i * 2 + 1] = sinf(f);
}

// ---------------------------------------------------------------------------
__global__ __launch_bounds__(256) void qkprep_k(
    bf16* __restrict__ qkv, const float* __restrict__ tab)
{
    int wid  = blockIdx.x * 4 + (threadIdx.x >> 6);
    int lane = threadIdx.x & 63;
    int s = wid & 1023, h = (wid >> 10) & 15, b = (wid >> 14) & 1, op = wid >> 15;
    bf16* addr = qkv + ((size_t)(b * 1024 + s)) * 3072 + op * 1024 + h * 64 + lane;
    float v = (float)*addr;
    float ss = v * v;
#pragma unroll
    for (int m = 1; m < 64; m <<= 1) ss += __shfl_xor(ss, m);
    v /= fmaxf(sqrtf(ss), 1e-5f);
    float2 cssn = ((const float2*)tab)[(s << 5) + (lane & 31)];
    float partner = __shfl_xor(v, 32);
    float o = (lane < 32) ? (v * cssn.x + partner * cssn.y)
                          : (v * cssn.x - partner * cssn.y);
    *addr = (bf16)o;
}

// ---------------------------------------------------------------------------
__global__ __launch_bounds__(256) void vtrans_k(
    const bf16* __restrict__ qkv, bf16* __restrict__ Vt)
{
    __shared__ __align__(16) bf16 Ls[64][72];
    const int st = blockIdx.x, h = blockIdx.y, b = blockIdx.z;
    const int tid = threadIdx.x;
#pragma unroll
    for (int p = 0; p < 2; p++) {
        int s = p * 32 + (tid >> 3), a0 = (tid & 7) << 3;
        *(bf16x8*)&Ls[s][a0] = *(const bf16x8*)(
            qkv + ((size_t)(b * 1024 + st * 64 + s)) * 3072 + 2048 + h * 64 + a0);
    }
    __syncthreads();
#pragma unroll
    for (int p = 0; p < 2; p++) {
        int a = p * 32 + (tid >> 3), s0 = (tid & 7) << 3;
        bf16x8 v;
#pragma unroll
        for (int j = 0; j < 8; j++) v[j] = Ls[s0 + j][a];
        *(bf16x8*)(Vt + (((size_t)((b * 16 + h) * 64 + a)) << 10) + st * 64 + s0) = v;
    }
}

// ---------------------------------------------------------------------------
// Flash attention, pipelined 64-key tiles.  Grid (16,16,2), 4 waves/block.
// Wave w of block p owns q-tile g = {p, 31-p, 32+p, 63-p}[w] (uniform work).
// Per iter: QK MFMAs -> issue V(cur)+K(next) loads -> softmax chain (hides
// load latency) -> P LDS transpose (wave-private, no barriers) -> PV MFMAs.
// Fully-masked leading tiles flush via alpha=exp(NEG-m)=0.
// ---------------------------------------------------------------------------
__global__ __launch_bounds__(256) void attn_k(
    const bf16* __restrict__ qkv, const bf16* __restrict__ Vt,
    const int* __restrict__ doc, bf16* __restrict__ attnb)
{
    const int p = blockIdx.x, h = blockIdx.y, b = blockIdx.z;
    const int tid = threadIdx.x, w = tid >> 6, lane = tid & 63;
    const int quad = lane >> 4, l16 = lane & 15;
    const float NEG = -30000.0f;
    __shared__ __align__(16) bf16 PsT[4][64][20];  // [wave][key][qrow+pad]
    __shared__ int docL[128];
    if (tid < 128) docL[tid] = doc[b * 128 + tid];
    __syncthreads();

    const int g = (w == 0) ? p : (w == 1) ? 31 - p : (w == 2) ? 32 + p : 63 - p;
    const bf16* qp = qkv + ((size_t)(b * 1024 + g * 16 + l16)) * 3072 + h * 64 + quad * 8;
    const bf16x8 qf0 = *(const bf16x8*)qp;
    const bf16x8 qf1 = *(const bf16x8*)(qp + 32);
    const bf16* Kbase = qkv + ((size_t)(b * 1024)) * 3072 + 1024 + h * 64;
    const bf16* Vbase = Vt + (((size_t)((b * 16 + h) * 64)) << 10);

    const f32x4 z4 = {0.f, 0.f, 0.f, 0.f};
    f32x4 O[4] = {z4, z4, z4, z4};
    float mrun[4], lrun[4];
#pragma unroll
    for (int r = 0; r < 4; r++) { mrun[r] = NEG; lrun[r] = 0.f; }

    bf16x8 kc[8], kn[8];   // K frags cur/next: [keygroup16 * 2 + half]
    auto loadK = [&](int kt, bf16x8* dst) {
        const bf16* kp = Kbase + (size_t)(kt * 64 + l16) * 3072 + quad * 8;
#pragma unroll
        for (int kg = 0; kg < 4; kg++) {
            dst[kg * 2]     = *(const bf16x8*)(kp + (size_t)kg * 16 * 3072);
            dst[kg * 2 + 1] = *(const bf16x8*)(kp + (size_t)kg * 16 * 3072 + 32);
        }
    };

    const int tiles = (g + 4) >> 2;   // ceil(16(g+1)/64)
    loadK(0, kc);
    for (int kt = 0; kt < tiles; kt++) {
        const int k0 = kt * 64;
        // --- QK^T: 8 MFMAs into 4 score frags (16 keys each) ---
        f32x4 sf[4];
#pragma unroll
        for (int kg = 0; kg < 4; kg++) {
            sf[kg] = z4;
            sf[kg] = MFMA16(qf0, kc[kg * 2],     sf[kg]);
            sf[kg] = MFMA16(qf1, kc[kg * 2 + 1], sf[kg]);
        }
        // --- issue prefetches: V for THIS tile + K for NEXT tile;
        //     their latency hides under the softmax chain below ---
        bf16x8 vr[4][2];
#pragma unroll
        for (int t = 0; t < 4; t++)
#pragma unroll
            for (int c = 0; c < 2; c++)
                vr[t][c] = *(const bf16x8*)(
                    Vbase + ((size_t)(t * 16 + l16) << 10) + k0 + c * 32 + quad * 8);
        if (kt + 1 < tiles) loadK(kt + 1, kn);

        // --- masked online softmax over 64 keys ---
        float alpha[4], pv[4][4];   // pv[kg][r]
#pragma unroll
        for (int r = 0; r < 4; r++) {
            int qg = g * 16 + quad * 4 + r;
            int bq = qg >> 3, dq = docL[bq];
            float sv[4];
#pragma unroll
            for (int kg = 0; kg < 4; kg++) {
                int kgi = k0 + kg * 16 + l16;
                int bk = kgi >> 3;
                bool ok = (bq == bk) || ((bq >= bk) && ((kgi & 7) < 4) && (dq == docL[bk]));
                sv[kg] = ok ? sf[kg][r] * 0.125f : NEG;
            }
            float mr = fmaxf(fmaxf(sv[0], sv[1]), fmaxf(sv[2], sv[3]));
#pragma unroll
            for (int m = 1; m < 16; m <<= 1) mr = fmaxf(mr, __shfl_xor(mr, m));
            float mn = fmaxf(mrun[r], mr);
            alpha[r] = __expf(mrun[r] - mn);
            float ls = 0.f;
#pragma unroll
            for (int kg = 0; kg < 4; kg++) {
                float pp = __expf(sv[kg] - mn);
                pv[kg][r] = pp;
                ls += pp;
            }
#pragma unroll
            for (int m = 1; m < 16; m <<= 1) ls += __shfl_xor(ls, m);
            lrun[r] = lrun[r] * alpha[r] + ls;
            mrun[r] = mn;
        }
        // --- P -> LDS (C layout) -> A-frag (wave-private, in-order DS) ---
#pragma unroll
        for (int kg = 0; kg < 4; kg++) {
            bf16x4 t4;
#pragma unroll
            for (int r = 0; r < 4; r++) t4[r] = (bf16)pv[kg][r];
            *(bf16x4*)&PsT[w][kg * 16 + l16][quad * 4] = t4;
        }
        bf16x8 pa0, pa1;
#pragma unroll
        for (int j = 0; j < 8; j++) {
            pa0[j] = PsT[w][quad * 8 + j][l16];
            pa1[j] = PsT[w][32 + quad * 8 + j][l16];
        }
        // --- rescale + PV: 8 MFMAs ---
#pragma unroll
        for (int t = 0; t < 4; t++) {
#pragma unroll
            for (int r = 0; r < 4; r++) O[t][r] *= alpha[r];
            O[t] = MFMA16(pa0, vr[t][0], O[t]);
            O[t] = MFMA16(pa1, vr[t][1], O[t]);
        }
        if (kt + 1 < tiles) {
#pragma unroll
            for (int i = 0; i < 8; i++) kc[i] = kn[i];
        }
    }

#pragma unroll
    for (int t = 0; t < 4; t++)
#pragma unroll
        for (int r = 0; r < 4; r++) {
            int qg = g * 16 + quad * 4 + r;
            float v = O[t][r] / fmaxf(lrun[r], 1e-20f);
            attnb[((size_t)(b * 1024) + qg) * 1024 + h * 64 + t * 16 + l16] = (bf16)v;
        }
}

// ---------------------------------------------------------------------------
__global__ __launch_bounds__(256) void permute_k(
    const bf16* __restrict__ t1, bf16* __restrict__ t1p)
{
    int idx = blockIdx.x * 256 + threadIdx.x;  // 262144
    int u = idx & 255, m = u >> 6, v = u & 63;
    int orow = idx >> 8;
    int k = orow & 3, bc = orow >> 2;
    int b = bc >> 7, c = bc & 127;
    t1p[idx] = t1[((size_t)(b * 512 + c * 4 + m)) * 256 + k * 64 + v];
}

__global__ __launch_bounds__(256) void buildx_k(
    const float* __restrict__ x_input, const float* __restrict__ t2,
    const float* __restrict__ pos_emb, float* __restrict__ xres)
{
    int idx = blockIdx.x * 256 + threadIdx.x;  // 2M
    int d = idx & 1023, row = idx >> 10;
    int b = row >> 10, rr = row & 1023;
    int c = rr >> 3, e = rr & 7;
    float v;
    if (e < 4)
        v = x_input[((size_t)(b * 512 + c * 4 + e)) * 1024 + d];
    else
        v = t2[((size_t)(b * 512 + c * 4 + (e - 4))) * 1024 + d] +
            pos_emb[(e - 4) * 1024 + d];
    xres[idx] = v;
}

__global__ __launch_bounds__(256) void finalout_k(
    const float* __restrict__ xres, float* __restrict__ out)
{
    int idx = blockIdx.x * 256 + threadIdx.x;  // 1M
    int d = idx & 1023, t = idx >> 10;
    int kk = t & 3, bc = t >> 2;
    int b = bc >> 7, c = bc & 127;
    out[idx] = xres[((size_t)(b * 1024 + c * 8 + 4 + kk)) * 1024 + d];
}

// ---------------------------------------------------------------------------
// Workspace (32 MB): same liveness plan as round 5/6.
// ---------------------------------------------------------------------------
extern "C" void kernel_launch(void* const* d_in, const int* in_sizes, int n_in,
                              void* d_out, int out_size, void* d_ws, size_t ws_size,
                              hipStream_t stream)
{
    const float* x_input = (const float*)d_in[0];
    const int*   doc     = (const int*)d_in[1];
    const float* dec_w1  = (const float*)d_in[2];
    const float* dec_w2  = (const float*)d_in[3];
    const float* pos_emb = (const float*)d_in[4];
    const float* Wqkv    = (const float*)d_in[5];
    const float* Wo      = (const float*)d_in[6];
    const float* Wup     = (const float*)d_in[7];
    const float* Wdown   = (const float*)d_in[8];
    const float* anw     = (const float*)d_in[9];
    const float* fnw     = (const float*)d_in[10];
    float* out = (float*)d_out;

    char* w = (char*)d_ws;
    float* xres  = (float*)(w);                    // [0,8)
    bf16*  attnb = (bf16*)(w + (8u << 20));        // [8,12)
    bf16*  t1    = (bf16*)(w + (8u << 20));        // prologue only
    bf16*  t1p   = (bf16*)(w + (8u << 20) + (512u << 10));
    bf16*  Vt    = (bf16*)(w + (12u << 20));       // [12,16)
    bf16*  xn2   = (bf16*)(w + (12u << 20));       // aliases Vt
    bf16*  qkv   = (bf16*)(w + (16u << 20));       // [16,28)
    float* t2    = (float*)(w + (16u << 20));      // [16,20) prologue only
    float* x1res = (float*)(w + (16u << 20));      // [16,24) (qkv dead post-attn)
    bf16*  hg    = (bf16*)(w + (24u << 20));       // [24,32)
    bf16*  xn1   = (bf16*)(w + (28u << 20));       // [28,32)
    float* rtab  = out;                            // 256 KB scratch in d_out

    // ---- prologue ----
    ropetab_k<<<128, 256, 0, stream>>>(rtab);
    gemm_bt<0, 1, 1, 64, 64><<<dim3(4, 16), 256, 0, stream>>>(
        x_input, dec_w1, nullptr, t1, 256, 1024, 1024);
    permute_k<<<1024, 256, 0, stream>>>(t1, t1p);
    gemm_bt<2, 0, 1, 64, 64><<<dim3(16, 16), 256, 0, stream>>>(
        t1p, dec_w2, nullptr, t2, 1024, 256, 256);
    buildx_k<<<8192, 256, 0, stream>>>(x_input, t2, pos_emb, xres);

    // ---- 4 transformer layers ----
    for (int li = 0; li < 4; ++li) {
        rmsnorm_k<<<2048, 256, 0, stream>>>(xres, anw + li * 1024, xn1);
        gemm_bt<0, 0, 1, 128, 128><<<dim3(24, 16), 256, 0, stream>>>(
            xn1, Wqkv + (size_t)li * 3072 * 1024, nullptr, qkv, 3072, 1024, 1024);
        qkprep_k<<<16384, 256, 0, stream>>>(qkv, rtab);
        vtrans_k<<<dim3(16, 16, 2), 256, 0, stream>>>(qkv, Vt);
        attn_k<<<dim3(16, 16, 2), 256, 0, stream>>>(qkv, Vt, doc, attnb);
        gemm_bt<1, 0, 1, 64, 64><<<dim3(16, 32), 256, 0, stream>>>(
            attnb, Wo + (size_t)li * 1024 * 1024, xres, x1res, 1024, 1024, 1024);
        rmsnorm_k<<<2048, 256, 0, stream>>>(x1res, fnw + li * 1024, xn2);
        gemm_up_swiglu<<<dim3(32, 16), 256, 0, stream>>>(
            xn2, Wup + (size_t)li * 4096 * 1024, hg);
        gemm_bt<1, 0, 1, 64, 64><<<dim3(16, 32), 256, 0, stream>>>(
            hg, Wdown + (size_t)li * 1024 * 2048, x1res, xres, 1024, 2048, 2048);
    }

    finalout_k<<<4096, 256, 0, stream>>>(xres, out);
}